// Round 10
// baseline (6320.944 us; speedup 1.0000x reference)
//
#include <hip/hip_runtime.h>
#include <math.h>

#define HDIM 128
#define ET 64          // edges (or nodes) per block
#define KC 32
#define M1STR 136      // m1 LDS row stride in bf16 (272 B, 16B-aligned)

typedef __attribute__((ext_vector_type(8))) short short8;
typedef __attribute__((ext_vector_type(4))) float f32x4;

__device__ __forceinline__ float silu_f(float x) {
    return x / (1.0f + __expf(-x));
}
__device__ __forceinline__ unsigned short f2bf(float f) {
    unsigned int u = __float_as_uint(f);
    u = (u + 0x7FFF + ((u >> 16) & 1)) >> 16;   // RNE
    return (unsigned short)u;
}
__device__ __forceinline__ float bf2f(unsigned short v) {
    return __uint_as_float(((unsigned int)v) << 16);
}

// ---------------------------------------------------------------------------
// h = x @ emb_W + emb_b    (N x 11 @ 11 x 128); also emit bf16 copy
// ---------------------------------------------------------------------------
__global__ __launch_bounds__(256) void embed_kernel(
    const float* __restrict__ x, const float* __restrict__ W,
    const float* __restrict__ b, float* __restrict__ h,
    unsigned short* __restrict__ hbf, int N)
{
    int n = blockIdx.x * 2 + (threadIdx.x >> 7);
    int j = threadIdx.x & 127;
    if (n >= N) return;
    float s = b[j];
#pragma unroll
    for (int k = 0; k < 11; ++k) s += x[n * 11 + k] * W[k * HDIM + j];
    h[(size_t)n * HDIM + j] = s;
    hbf[(size_t)n * HDIM + j] = f2bf(s);
}

// ---------------------------------------------------------------------------
// Counting sort of edges by row (destination). Done once per launch.
// ---------------------------------------------------------------------------
__global__ __launch_bounds__(256) void count_kernel(
    const int* __restrict__ row, int* __restrict__ cnt, int E)
{
    int e = blockIdx.x * 256 + threadIdx.x;
    if (e < E) atomicAdd(&cnt[row[e]], 1);
}

__global__ __launch_bounds__(1024) void scan_kernel(
    const int* __restrict__ cnt, int* __restrict__ cursor, int Nn)
{
    __shared__ int lds[1024];
    int t = threadIdx.x;
    int chunk = (Nn + 1023) >> 10;
    int base = t * chunk;
    int s = 0;
    for (int k = 0; k < chunk; ++k) {
        int n = base + k;
        if (n < Nn) s += cnt[n];
    }
    lds[t] = s;
    __syncthreads();
    for (int d = 1; d < 1024; d <<= 1) {
        int v = (t >= d) ? lds[t - d] : 0;
        __syncthreads();
        lds[t] += v;
        __syncthreads();
    }
    int run = lds[t] - s;
    for (int k = 0; k < chunk; ++k) {
        int n = base + k;
        if (n < Nn) { cursor[n] = run; run += cnt[n]; }
    }
}

__global__ __launch_bounds__(256) void scatter_kernel(
    const int* __restrict__ row, const int* __restrict__ col,
    int* __restrict__ cursor, int* __restrict__ srow, int* __restrict__ scol, int E)
{
    int e = blockIdx.x * 256 + threadIdx.x;
    if (e < E) {
        int r = row[e];
        int p = atomicAdd(&cursor[r], 1);
        srow[p] = r;
        scol[p] = col[e];
    }
}

// ---------------------------------------------------------------------------
// Prepack edge weights into bf16 MFMA B-fragment order, SPLIT hi/lo:
//   lo = bf16(W - float(hi)).  Layout per layer: [kt][ph][ct][lane][j]
// ---------------------------------------------------------------------------
__global__ __launch_bounds__(256) void pack_w1_kernel(
    const float* __restrict__ ew1, unsigned short* __restrict__ w1p)
{
    int idx = blockIdx.x * 256 + threadIdx.x;       // 16384 total
    int l    = idx >> 12;
    int kt   = (idx >> 9) & 7;
    int ct   = (idx >> 6) & 7;
    int lane = idx & 63;
    const float* src = ew1 + (size_t)l * 257 * HDIM;
    short8 hi, lo;
#pragma unroll
    for (int j = 0; j < 8; ++j) {
        float w = src[(size_t)(kt * 32 + (lane >> 4) * 8 + j) * HDIM + ct * 16 + (lane & 15)];
        unsigned short h = f2bf(w);
        hi[j] = (short)h;
        lo[j] = (short)f2bf(w - bf2f(h));
    }
    size_t base = (size_t)l * 65536;
    *(short8*)(w1p + base + ((size_t)((kt * 2 + 0) * 8 + ct) * 64 + lane) * 8) = hi;
    *(short8*)(w1p + base + ((size_t)((kt * 2 + 1) * 8 + ct) * 64 + lane) * 8) = lo;
}

__global__ __launch_bounds__(256) void pack_w2_kernel(
    const float* __restrict__ ew2, unsigned short* __restrict__ w2p)
{
    int idx = blockIdx.x * 256 + threadIdx.x;       // 8192 total
    int l    = idx >> 11;
    int kt   = (idx >> 9) & 3;
    int ct   = (idx >> 6) & 7;
    int lane = idx & 63;
    const float* src = ew2 + (size_t)l * HDIM * HDIM;
    short8 hi, lo;
#pragma unroll
    for (int j = 0; j < 8; ++j) {
        float w = src[(size_t)(kt * 32 + (lane >> 4) * 8 + j) * HDIM + ct * 16 + (lane & 15)];
        unsigned short h = f2bf(w);
        hi[j] = (short)h;
        lo[j] = (short)f2bf(w - bf2f(h));
    }
    size_t base = (size_t)l * 32768;
    *(short8*)(w2p + base + ((size_t)((kt * 2 + 0) * 8 + ct) * 64 + lane) * 8) = hi;
    *(short8*)(w2p + base + ((size_t)((kt * 2 + 1) * 8 + ct) * 64 + lane) * 8) = lo;
}

// ---------------------------------------------------------------------------
// Barrier-light MFMA edge kernel, register-resident flush. 64 edges/block,
// 4 waves; wave wv owns output cols [wv*32, wv*32+32) of ALL 64 edges.
// Segments (runs of equal row) precomputed via ballot; agg flushed straight
// from accumulators with predicated per-segment sums (no fp32 LDS staging).
// 3 barriers total; LDS ~20.5 KB -> ~7 blocks/CU.
// ---------------------------------------------------------------------------
__global__ __launch_bounds__(256, 6) void edge_kernel(
    const unsigned short* __restrict__ hbf,  // [N,128] bf16
    const float* __restrict__ pos,           // [N,3]
    const int*   __restrict__ row,           // sorted
    const int*   __restrict__ col,
    const unsigned short* __restrict__ w1p,  // [8][2][8][64][8] bf16 frags
    const float* __restrict__ w1r256,        // W1 row 256 (f32[128])
    const float* __restrict__ b1,            // [128]
    const unsigned short* __restrict__ w2p,  // [4][2][8][64][8]
    const float* __restrict__ b2,            // [128]
    const float* __restrict__ cw,            // [128]
    const float* __restrict__ cb,            // [1]
    float* __restrict__ agg,                 // [N,128]
    float* __restrict__ posn)                // [N,3]
{
    __shared__ __align__(16) short m1lds[ET * M1STR];    // 17.4 KB
    __shared__ float diff_lds[3][ET];
    __shared__ float dist2_lds[ET];
    __shared__ float pdot[4][ET];
    __shared__ int   row_lds[ET];
    __shared__ int   col_lds[ET];
    __shared__ int   seg_start[ET + 2];                  // [0..S], sentinel at S
    __shared__ int   seg_row[ET];
    __shared__ int   nseg;

    const int tid  = threadIdx.x;
    const int lane = tid & 63;
    const int wv   = tid >> 6;
    const int cbase = lane & 15;
    const int kgrp  = lane >> 4;
    const long long e0 = (long long)blockIdx.x * ET;

    if (tid < ET) {
        long long e = e0 + tid;
        int r = row[e], c = col[e];
        int rprev = (tid > 0) ? row[e - 1] : -1;
        row_lds[tid] = r; col_lds[tid] = c;
        float dx = pos[r * 3 + 0] - pos[c * 3 + 0];
        float dy = pos[r * 3 + 1] - pos[c * 3 + 1];
        float dz = pos[r * 3 + 2] - pos[c * 3 + 2];
        diff_lds[0][tid] = dx; diff_lds[1][tid] = dy; diff_lds[2][tid] = dz;
        dist2_lds[tid] = dx * dx + dy * dy + dz * dz;
        // segment structure (wave 0 only, tid==lane here)
        bool flag = (tid == 0) || (r != rprev);
        unsigned long long mask = __ballot(flag);
        int sid = __popcll(mask & (((unsigned long long)1 << tid) - 1));
        if (flag) { seg_start[sid] = tid; seg_row[sid] = r; }
        if (tid == 63) { int S = __popcll(mask); nseg = S; seg_start[S] = ET; }
    }
    __syncthreads();                                     // B1

    // per-lane A-row node indices (A-row = lane&15 within each 16-edge tile)
    int ridx[4], cidx[4];
#pragma unroll
    for (int ea = 0; ea < 4; ++ea) {
        ridx[ea] = row_lds[ea * 16 + cbase];
        cidx[ea] = col_lds[ea * 16 + cbase];
    }

    // ---- MLP1: K=256, B-frags direct from L2, no barriers ----
    f32x4 acc[4][2];
#pragma unroll
    for (int ea = 0; ea < 4; ++ea)
#pragma unroll
        for (int ci = 0; ci < 2; ++ci) acc[ea][ci] = (f32x4){0.f, 0.f, 0.f, 0.f};

#pragma unroll
    for (int kt = 0; kt < 8; ++kt) {
        short8 a[4];
#pragma unroll
        for (int ea = 0; ea < 4; ++ea) {
            int idx = (kt < 4) ? ridx[ea] : cidx[ea];
            a[ea] = *(const short8*)(hbf + (size_t)idx * HDIM + (kt & 3) * 32 + kgrp * 8);
        }
#pragma unroll
        for (int ph = 0; ph < 2; ++ph) {
            short8 bA = *(const short8*)(w1p + ((size_t)((kt * 2 + ph) * 8 + wv * 2 + 0) * 64 + lane) * 8);
            short8 bB = *(const short8*)(w1p + ((size_t)((kt * 2 + ph) * 8 + wv * 2 + 1) * 64 + lane) * 8);
#pragma unroll
            for (int ea = 0; ea < 4; ++ea) {
                acc[ea][0] = __builtin_amdgcn_mfma_f32_16x16x32_bf16(a[ea], bA, acc[ea][0], 0, 0, 0);
                acc[ea][1] = __builtin_amdgcn_mfma_f32_16x16x32_bf16(a[ea], bB, acc[ea][1], 0, 0, 0);
            }
        }
    }

    // ---- dist2 row + bias + silu -> m1 (bf16) into LDS [e][c] ----
    {
        float w256v[2], b1v[2];
#pragma unroll
        for (int ci = 0; ci < 2; ++ci) {
            int c = wv * 32 + ci * 16 + cbase;
            w256v[ci] = w1r256[c];
            b1v[ci]   = b1[c];
        }
#pragma unroll
        for (int ea = 0; ea < 4; ++ea)
#pragma unroll
            for (int ci = 0; ci < 2; ++ci)
#pragma unroll
                for (int rr = 0; rr < 4; ++rr) {
                    int e = ea * 16 + kgrp * 4 + rr;
                    float v = silu_f(acc[ea][ci][rr] + dist2_lds[e] * w256v[ci] + b1v[ci]);
                    m1lds[e * M1STR + wv * 32 + ci * 16 + cbase] = (short)f2bf(v);
                }
    }
    __syncthreads();                                     // B2: m1 ready

    // ---- MLP2: K=128, A from LDS m1, B direct from L2, no barriers ----
    f32x4 acc2[4][2];
#pragma unroll
    for (int ea = 0; ea < 4; ++ea)
#pragma unroll
        for (int ci = 0; ci < 2; ++ci) acc2[ea][ci] = (f32x4){0.f, 0.f, 0.f, 0.f};

#pragma unroll
    for (int kt = 0; kt < 4; ++kt) {
        short8 a[4];
#pragma unroll
        for (int ea = 0; ea < 4; ++ea)
            a[ea] = *(const short8*)&m1lds[(ea * 16 + cbase) * M1STR + kt * 32 + kgrp * 8];
#pragma unroll
        for (int ph = 0; ph < 2; ++ph) {
            short8 bA = *(const short8*)(w2p + ((size_t)((kt * 2 + ph) * 8 + wv * 2 + 0) * 64 + lane) * 8);
            short8 bB = *(const short8*)(w2p + ((size_t)((kt * 2 + ph) * 8 + wv * 2 + 1) * 64 + lane) * 8);
#pragma unroll
            for (int ea = 0; ea < 4; ++ea) {
                acc2[ea][0] = __builtin_amdgcn_mfma_f32_16x16x32_bf16(a[ea], bA, acc2[ea][0], 0, 0, 0);
                acc2[ea][1] = __builtin_amdgcn_mfma_f32_16x16x32_bf16(a[ea], bB, acc2[ea][1], 0, 0, 0);
            }
        }
    }

    // ---- epilogue: m = silu(acc2+b2) kept in REGISTERS; coord partials ----
    {
        float b2v[2], cwv2[2];
#pragma unroll
        for (int ci = 0; ci < 2; ++ci) {
            int c = wv * 32 + ci * 16 + cbase;
            b2v[ci]  = b2[c];
            cwv2[ci] = cw[c];
        }
#pragma unroll
        for (int ea = 0; ea < 4; ++ea)
#pragma unroll
            for (int rr = 0; rr < 4; ++rr) {
                int e = ea * 16 + kgrp * 4 + rr;
                float p = 0.f;
#pragma unroll
                for (int ci = 0; ci < 2; ++ci) {
                    float v = silu_f(acc2[ea][ci][rr] + b2v[ci]);
                    acc2[ea][ci][rr] = v;
                    p += v * cwv2[ci];
                }
#pragma unroll
                for (int d = 8; d >= 1; d >>= 1) p += __shfl_xor(p, d);
                if (cbase == 0) pdot[wv][e] = p;
            }
    }
    __syncthreads();                                     // B3: pdot ready

    if (tid < ET) {
        float t = tanhf(pdot[0][tid] + pdot[1][tid] + pdot[2][tid] + pdot[3][tid] + cb[0]);
        diff_lds[0][tid] *= t;
        diff_lds[1][tid] *= t;
        diff_lds[2][tid] *= t;
    }

    // ---- register-resident segmented agg flush ----
    {
        const int S = nseg;
        for (int s = 0; s < S; ++s) {
            int lo = seg_start[s], hi = seg_start[s + 1];
            int rw = seg_row[s];
            float sm0 = 0.f, sm1 = 0.f;
#pragma unroll
            for (int ea = 0; ea < 4; ++ea)
#pragma unroll
                for (int rr = 0; rr < 4; ++rr) {
                    int e = ea * 16 + kgrp * 4 + rr;
                    bool in = (e >= lo) && (e < hi);
                    sm0 += in ? acc2[ea][0][rr] : 0.f;
                    sm1 += in ? acc2[ea][1][rr] : 0.f;
                }
            sm0 += __shfl_xor(sm0, 16); sm0 += __shfl_xor(sm0, 32);
            sm1 += __shfl_xor(sm1, 16); sm1 += __shfl_xor(sm1, 32);
            if (kgrp == 0) {
                atomicAdd(&agg[(size_t)rw * HDIM + wv * 32 + cbase], sm0);
                atomicAdd(&agg[(size_t)rw * HDIM + wv * 32 + 16 + cbase], sm1);
            }
        }
    }

    // ---- pos flush (wave 0 internal; diff scaled by tid<64 of same wave) ----
    if (tid < 3) {
        int d = tid;
        float a = 0.0f;
        int prev = row_lds[0];
        for (int e = 0; e < ET; ++e) {
            int r = row_lds[e];
            if (r != prev) {
                atomicAdd(&posn[(size_t)prev * 3 + d], a);
                a = 0.0f; prev = r;
            }
            a += diff_lds[d][e];
        }
        atomicAdd(&posn[(size_t)prev * 3 + d], a);
    }
}

// ---------------------------------------------------------------------------
// h_out = silu(concat[h, agg] @ NW + nb)   (K = 256); also emit bf16 copy
// ---------------------------------------------------------------------------
__global__ __launch_bounds__(256, 2) void node_kernel(
    const float* __restrict__ h, const float* __restrict__ agg,
    const float* __restrict__ W,   // [256][128]
    const float* __restrict__ nb,  // [128]
    float* __restrict__ hout, unsigned short* __restrict__ houtbf, int N)
{
    __shared__ float Wlds[KC * HDIM];
    __shared__ float abuf[ET * 36];

    const int tid = threadIdx.x;
    const int n0 = blockIdx.x * ET;
    const int jq8 = (tid & 15) * 8;
    const int eg4 = (tid >> 4) * 4;
    const int gl_e = tid >> 2;
    const int gl_k = (tid & 3) * 8;

    float acc[4][8];
#pragma unroll
    for (int i = 0; i < 4; ++i)
#pragma unroll
        for (int j = 0; j < 8; ++j) acc[i][j] = 0.0f;

    for (int c = 0; c < 8; ++c) {
        {
            const float4* src = (const float4*)(W + (size_t)c * KC * HDIM);
            float4* dst = (float4*)Wlds;
#pragma unroll
            for (int t = 0; t < 4; ++t) dst[tid + t * 256] = src[tid + t * 256];
        }
        {
            int n = n0 + gl_e;
            int koff = (c & 3) * KC;
            float4* adst = (float4*)(abuf + gl_e * 36 + gl_k);
            if (n < N) {
                const float* base = (c < 4) ? h : agg;
                const float4* asrc = (const float4*)(base + (size_t)n * HDIM + koff + gl_k);
                adst[0] = asrc[0]; adst[1] = asrc[1];
            } else {
                float4 z = make_float4(0.f, 0.f, 0.f, 0.f);
                adst[0] = z; adst[1] = z;
            }
        }
        __syncthreads();
#pragma unroll 8
        for (int kk = 0; kk < KC; ++kk) {
            float a0 = abuf[(eg4 + 0) * 36 + kk];
            float a1 = abuf[(eg4 + 1) * 36 + kk];
            float a2 = abuf[(eg4 + 2) * 36 + kk];
            float a3 = abuf[(eg4 + 3) * 36 + kk];
            float4 w0 = *(const float4*)&Wlds[kk * HDIM + jq8];
            float4 w1 = *(const float4*)&Wlds[kk * HDIM + jq8 + 4];
            float w[8] = {w0.x, w0.y, w0.z, w0.w, w1.x, w1.y, w1.z, w1.w};
            float a[4] = {a0, a1, a2, a3};
#pragma unroll
            for (int i = 0; i < 4; ++i)
#pragma unroll
                for (int j = 0; j < 8; ++j) acc[i][j] += a[i] * w[j];
        }
        __syncthreads();
    }

    float bb[8];
    *(float4*)&bb[0] = *(const float4*)(nb + jq8);
    *(float4*)&bb[4] = *(const float4*)(nb + jq8 + 4);
#pragma unroll
    for (int i = 0; i < 4; ++i) {
        int n = n0 + eg4 + i;
        if (n < N) {
            float v[8];
#pragma unroll
            for (int j = 0; j < 8; ++j) v[j] = silu_f(acc[i][j] + bb[j]);
            *(float4*)(hout + (size_t)n * HDIM + jq8)     = make_float4(v[0], v[1], v[2], v[3]);
            *(float4*)(hout + (size_t)n * HDIM + jq8 + 4) = make_float4(v[4], v[5], v[6], v[7]);
            unsigned short* hb = houtbf + (size_t)n * HDIM + jq8;
#pragma unroll
            for (int j = 0; j < 8; ++j) hb[j] = f2bf(v[j]);
        }
    }
}

// ---------------------------------------------------------------------------
__global__ __launch_bounds__(256) void pool_kernel(
    const float* __restrict__ h, const int* __restrict__ batch,
    float* __restrict__ pooled, float* __restrict__ cnt, int N)
{
    int idx = blockIdx.x * 256 + threadIdx.x;
    int n = idx >> 5;
    int jg = idx & 31;
    if (n >= N) return;
    int b = batch[n];
    float4 v = *(const float4*)(h + (size_t)n * HDIM + jg * 4);
    atomicAdd(&pooled[(size_t)b * HDIM + jg * 4 + 0], v.x);
    atomicAdd(&pooled[(size_t)b * HDIM + jg * 4 + 1], v.y);
    atomicAdd(&pooled[(size_t)b * HDIM + jg * 4 + 2], v.z);
    atomicAdd(&pooled[(size_t)b * HDIM + jg * 4 + 3], v.w);
    if (jg == 0) atomicAdd(&cnt[b], 1.0f);
}

// ---------------------------------------------------------------------------
__global__ __launch_bounds__(128) void head_kernel(
    const float* __restrict__ pooled, const float* __restrict__ cnt,
    const float* __restrict__ W1, const float* __restrict__ b1,
    const float* __restrict__ w2, const float* __restrict__ b2,
    float* __restrict__ out)
{
    __shared__ float p[HDIM];
    __shared__ float red[2];
    int g = blockIdx.x, j = threadIdx.x;
    float c = fmaxf(cnt[g], 1.0f);
    p[j] = pooled[(size_t)g * HDIM + j] / c;
    __syncthreads();
    float s = b1[j];
#pragma unroll 8
    for (int k = 0; k < HDIM; ++k) s += p[k] * W1[k * HDIM + j];
    float contrib = silu_f(s) * w2[j];
#pragma unroll
    for (int d = 32; d >= 1; d >>= 1) contrib += __shfl_xor(contrib, d);
    if ((j & 63) == 0) red[j >> 6] = contrib;
    __syncthreads();
    if (j == 0) out[g] = red[0] + red[1] + b2[0];
}

// ---------------------------------------------------------------------------
extern "C" void kernel_launch(void* const* d_in, const int* in_sizes, int n_in,
                              void* d_out, int out_size, void* d_ws, size_t ws_size,
                              hipStream_t stream)
{
    const float* x      = (const float*)d_in[0];
    const float* pos_in = (const float*)d_in[1];
    const int*   ei     = (const int*)d_in[2];
    const int*   batch  = (const int*)d_in[3];
    const float* emb_W  = (const float*)d_in[4];
    const float* emb_b  = (const float*)d_in[5];
    const float* ew1    = (const float*)d_in[6];
    const float* eb1    = (const float*)d_in[7];
    const float* ew2    = (const float*)d_in[8];
    const float* eb2    = (const float*)d_in[9];
    const float* nw     = (const float*)d_in[10];
    const float* nb     = (const float*)d_in[11];
    const float* cwv    = (const float*)d_in[12];
    const float* cbv    = (const float*)d_in[13];
    const float* hw1    = (const float*)d_in[14];
    const float* hb1    = (const float*)d_in[15];
    const float* hw2    = (const float*)d_in[16];
    const float* hb2    = (const float*)d_in[17];
    float* out = (float*)d_out;

    const int N = in_sizes[0] / 11;
    const int E = in_sizes[2] / 2;
    const int G = out_size;
    const int* row = ei;
    const int* col = ei + E;

    float* ws = (float*)d_ws;
    float* hA     = ws;
    float* hB     = hA  + (size_t)N * HDIM;
    float* agg    = hB  + (size_t)N * HDIM;
    float* hbf_f  = agg + (size_t)N * HDIM;        // N*128 bf16 = N*64 floats
    unsigned short* hbf = (unsigned short*)hbf_f;
    float* w1p_f  = hbf_f + (size_t)N * 64;        // 4*65536 bf16 = 131072 floats
    unsigned short* w1p = (unsigned short*)w1p_f;
    float* w2p_f  = w1p_f + 131072;                // 4*32768 bf16 = 65536 floats
    unsigned short* w2p = (unsigned short*)w2p_f;
    float* posA   = w2p_f + 65536;
    float* posB   = posA + (size_t)N * 3;
    float* pooled = posB + (size_t)N * 3;
    float* cnt    = pooled + (size_t)G * HDIM;
    int*   srow   = (int*)(cnt + G);
    int*   scol   = srow + E;
    int*   cntN   = scol + E;
    int*   curN   = cntN + N;

    // ---- counting sort of edges by row (layer-invariant) ----
    hipMemsetAsync(cntN, 0, (size_t)N * sizeof(int), stream);
    count_kernel<<<(E + 255) / 256, 256, 0, stream>>>(row, cntN, E);
    scan_kernel<<<1, 1024, 0, stream>>>(cntN, curN, N);
    scatter_kernel<<<(E + 255) / 256, 256, 0, stream>>>(row, col, curN, srow, scol, E);

    // ---- prepack edge weights to split-bf16 fragment order ----
    pack_w1_kernel<<<64, 256, 0, stream>>>(ew1, w1p);
    pack_w2_kernel<<<32, 256, 0, stream>>>(ew2, w2p);

    embed_kernel<<<(N + 1) / 2, 256, 0, stream>>>(x, emb_W, emb_b, hA, hbf, N);

    const float* hcur = hA;
    float* hnext = hB;
    const float* pcur = pos_in;
    float* pbufs[2] = {posA, posB};

    for (int l = 0; l < 4; ++l) {
        float* pn = pbufs[l & 1];
        hipMemsetAsync(agg, 0, (size_t)N * HDIM * sizeof(float), stream);
        hipMemcpyAsync(pn, pcur, (size_t)N * 3 * sizeof(float),
                       hipMemcpyDeviceToDevice, stream);
        edge_kernel<<<E / ET, 256, 0, stream>>>(
            hbf, pcur, srow, scol,
            w1p + (size_t)l * 65536,
            ew1 + (size_t)l * 257 * HDIM + 256 * HDIM,
            eb1 + (size_t)l * HDIM,
            w2p + (size_t)l * 32768,
            eb2 + (size_t)l * HDIM,
            cwv + (size_t)l * HDIM, cbv + l,
            agg, pn);
        node_kernel<<<(N + ET - 1) / ET, 256, 0, stream>>>(
            hcur, agg, nw + (size_t)l * 256 * HDIM, nb + (size_t)l * HDIM,
            hnext, hbf, N);
        const float* th = hcur; hcur = hnext; hnext = (float*)th;
        pcur = pn;
    }

    hipMemsetAsync(pooled, 0, (size_t)G * (HDIM + 1) * sizeof(float), stream);
    pool_kernel<<<(N * 32 + 255) / 256, 256, 0, stream>>>(hcur, batch, pooled, cnt, N);
    head_kernel<<<G, 128, 0, stream>>>(pooled, cnt, hw1, hb1, hw2, hb2, out);
}

// Round 12
// 5881.723 us; speedup vs baseline: 1.0747x; 1.0747x over previous
//
#include <hip/hip_runtime.h>
#include <math.h>

#define HDIM 128
#define ET 64          // edges (or nodes) per block
#define KC 32
#define M1STR 136      // m1 LDS row stride in bf16 (272 B, 16B-aligned)

typedef __attribute__((ext_vector_type(8))) short short8;
typedef __attribute__((ext_vector_type(4))) float f32x4;

__device__ __forceinline__ float silu_f(float x) {
    return x / (1.0f + __expf(-x));
}
__device__ __forceinline__ unsigned short f2bf(float f) {
    unsigned int u = __float_as_uint(f);
    u = (u + 0x7FFF + ((u >> 16) & 1)) >> 16;   // RNE
    return (unsigned short)u;
}
__device__ __forceinline__ float bf2f(unsigned short v) {
    return __uint_as_float(((unsigned int)v) << 16);
}

// ---------------------------------------------------------------------------
// h = x @ emb_W + emb_b    (N x 11 @ 11 x 128); also emit bf16 copy
// ---------------------------------------------------------------------------
__global__ __launch_bounds__(256) void embed_kernel(
    const float* __restrict__ x, const float* __restrict__ W,
    const float* __restrict__ b, float* __restrict__ h,
    unsigned short* __restrict__ hbf, int N)
{
    int n = blockIdx.x * 2 + (threadIdx.x >> 7);
    int j = threadIdx.x & 127;
    if (n >= N) return;
    float s = b[j];
#pragma unroll
    for (int k = 0; k < 11; ++k) s += x[n * 11 + k] * W[k * HDIM + j];
    h[(size_t)n * HDIM + j] = s;
    hbf[(size_t)n * HDIM + j] = f2bf(s);
}

// ---------------------------------------------------------------------------
// Counting sort of edges by row (destination). Done once per launch.
// ---------------------------------------------------------------------------
__global__ __launch_bounds__(256) void count_kernel(
    const int* __restrict__ row, int* __restrict__ cnt, int E)
{
    int e = blockIdx.x * 256 + threadIdx.x;
    if (e < E) atomicAdd(&cnt[row[e]], 1);
}

__global__ __launch_bounds__(1024) void scan_kernel(
    const int* __restrict__ cnt, int* __restrict__ cursor, int Nn)
{
    __shared__ int lds[1024];
    int t = threadIdx.x;
    int chunk = (Nn + 1023) >> 10;
    int base = t * chunk;
    int s = 0;
    for (int k = 0; k < chunk; ++k) {
        int n = base + k;
        if (n < Nn) s += cnt[n];
    }
    lds[t] = s;
    __syncthreads();
    for (int d = 1; d < 1024; d <<= 1) {
        int v = (t >= d) ? lds[t - d] : 0;
        __syncthreads();
        lds[t] += v;
        __syncthreads();
    }
    int run = lds[t] - s;
    for (int k = 0; k < chunk; ++k) {
        int n = base + k;
        if (n < Nn) { cursor[n] = run; run += cnt[n]; }
    }
}

__global__ __launch_bounds__(256) void scatter_kernel(
    const int* __restrict__ row, const int* __restrict__ col,
    int* __restrict__ cursor, int* __restrict__ srow, int* __restrict__ scol, int E)
{
    int e = blockIdx.x * 256 + threadIdx.x;
    if (e < E) {
        int r = row[e];
        int p = atomicAdd(&cursor[r], 1);
        srow[p] = r;
        scol[p] = col[e];
    }
}

// ---------------------------------------------------------------------------
// Prepack edge weights into bf16 MFMA B-fragment order, SPLIT hi/lo:
//   lo = bf16(W - float(hi)).  Layout per layer: [kt][ph][ct][lane][j]
// ---------------------------------------------------------------------------
__global__ __launch_bounds__(256) void pack_w1_kernel(
    const float* __restrict__ ew1, unsigned short* __restrict__ w1p)
{
    int idx = blockIdx.x * 256 + threadIdx.x;       // 16384 total
    int l    = idx >> 12;
    int kt   = (idx >> 9) & 7;
    int ct   = (idx >> 6) & 7;
    int lane = idx & 63;
    const float* src = ew1 + (size_t)l * 257 * HDIM;
    short8 hi, lo;
#pragma unroll
    for (int j = 0; j < 8; ++j) {
        float w = src[(size_t)(kt * 32 + (lane >> 4) * 8 + j) * HDIM + ct * 16 + (lane & 15)];
        unsigned short h = f2bf(w);
        hi[j] = (short)h;
        lo[j] = (short)f2bf(w - bf2f(h));
    }
    size_t base = (size_t)l * 65536;
    *(short8*)(w1p + base + ((size_t)((kt * 2 + 0) * 8 + ct) * 64 + lane) * 8) = hi;
    *(short8*)(w1p + base + ((size_t)((kt * 2 + 1) * 8 + ct) * 64 + lane) * 8) = lo;
}

__global__ __launch_bounds__(256) void pack_w2_kernel(
    const float* __restrict__ ew2, unsigned short* __restrict__ w2p)
{
    int idx = blockIdx.x * 256 + threadIdx.x;       // 8192 total
    int l    = idx >> 11;
    int kt   = (idx >> 9) & 3;
    int ct   = (idx >> 6) & 7;
    int lane = idx & 63;
    const float* src = ew2 + (size_t)l * HDIM * HDIM;
    short8 hi, lo;
#pragma unroll
    for (int j = 0; j < 8; ++j) {
        float w = src[(size_t)(kt * 32 + (lane >> 4) * 8 + j) * HDIM + ct * 16 + (lane & 15)];
        unsigned short h = f2bf(w);
        hi[j] = (short)h;
        lo[j] = (short)f2bf(w - bf2f(h));
    }
    size_t base = (size_t)l * 32768;
    *(short8*)(w2p + base + ((size_t)((kt * 2 + 0) * 8 + ct) * 64 + lane) * 8) = hi;
    *(short8*)(w2p + base + ((size_t)((kt * 2 + 1) * 8 + ct) * 64 + lane) * 8) = lo;
}

// ---------------------------------------------------------------------------
// Barrier-light MFMA edge kernel, register-resident flush. 64 edges/block,
// 4 waves; wave wv owns output cols [wv*32, wv*32+32) of ALL 64 edges.
// Segments (runs of equal row) precomputed via ballot; agg flushed straight
// from accumulators with predicated per-segment sums (no fp32 LDS staging).
// 3 barriers total; LDS ~21 KB. launch_bounds(256,5): VGPR cap 102 -> NO
// SPILL (round 10's (256,6) cap 85 spilled acc2 -> 2.1 GB scratch traffic).
// ---------------------------------------------------------------------------
__global__ __launch_bounds__(256, 5) void edge_kernel(
    const unsigned short* __restrict__ hbf,  // [N,128] bf16
    const float* __restrict__ pos,           // [N,3]
    const int*   __restrict__ row,           // sorted
    const int*   __restrict__ col,
    const unsigned short* __restrict__ w1p,  // [8][2][8][64][8] bf16 frags
    const float* __restrict__ w1r256,        // W1 row 256 (f32[128])
    const float* __restrict__ b1,            // [128]
    const unsigned short* __restrict__ w2p,  // [4][2][8][64][8]
    const float* __restrict__ b2,            // [128]
    const float* __restrict__ cw,            // [128]
    const float* __restrict__ cb,            // [1]
    float* __restrict__ agg,                 // [N,128]
    float* __restrict__ posn)                // [N,3]
{
    __shared__ __align__(16) short m1lds[ET * M1STR];    // 17.4 KB
    __shared__ float diff_lds[3][ET];
    __shared__ float dist2_lds[ET];
    __shared__ float pdot[4][ET];
    __shared__ int   row_lds[ET];
    __shared__ int   col_lds[ET];
    __shared__ int   seg_start[ET + 2];                  // [0..S], sentinel at S
    __shared__ int   seg_row[ET];
    __shared__ int   nseg;

    const int tid  = threadIdx.x;
    const int lane = tid & 63;
    const int wv   = tid >> 6;
    const int cbase = lane & 15;
    const int kgrp  = lane >> 4;
    const long long e0 = (long long)blockIdx.x * ET;

    if (tid < ET) {
        long long e = e0 + tid;
        int r = row[e], c = col[e];
        int rprev = (tid > 0) ? row[e - 1] : -1;
        row_lds[tid] = r; col_lds[tid] = c;
        float dx = pos[r * 3 + 0] - pos[c * 3 + 0];
        float dy = pos[r * 3 + 1] - pos[c * 3 + 1];
        float dz = pos[r * 3 + 2] - pos[c * 3 + 2];
        diff_lds[0][tid] = dx; diff_lds[1][tid] = dy; diff_lds[2][tid] = dz;
        dist2_lds[tid] = dx * dx + dy * dy + dz * dz;
        // segment structure (wave 0 only, tid==lane here)
        bool flag = (tid == 0) || (r != rprev);
        unsigned long long mask = __ballot(flag);
        int sid = __popcll(mask & (((unsigned long long)1 << tid) - 1));
        if (flag) { seg_start[sid] = tid; seg_row[sid] = r; }
        if (tid == 63) { int S = __popcll(mask); nseg = S; seg_start[S] = ET; }
    }
    __syncthreads();                                     // B1

    // per-lane A-row node indices (A-row = lane&15 within each 16-edge tile)
    int ridx[4], cidx[4];
#pragma unroll
    for (int ea = 0; ea < 4; ++ea) {
        ridx[ea] = row_lds[ea * 16 + cbase];
        cidx[ea] = col_lds[ea * 16 + cbase];
    }

    // ---- MLP1: K=256, B-frags direct from L2, no barriers ----
    f32x4 acc[4][2];
#pragma unroll
    for (int ea = 0; ea < 4; ++ea)
#pragma unroll
        for (int ci = 0; ci < 2; ++ci) acc[ea][ci] = (f32x4){0.f, 0.f, 0.f, 0.f};

#pragma unroll
    for (int kt = 0; kt < 8; ++kt) {
        short8 a[4];
#pragma unroll
        for (int ea = 0; ea < 4; ++ea) {
            int idx = (kt < 4) ? ridx[ea] : cidx[ea];
            a[ea] = *(const short8*)(hbf + (size_t)idx * HDIM + (kt & 3) * 32 + kgrp * 8);
        }
#pragma unroll
        for (int ph = 0; ph < 2; ++ph) {
            short8 bA = *(const short8*)(w1p + ((size_t)((kt * 2 + ph) * 8 + wv * 2 + 0) * 64 + lane) * 8);
            short8 bB = *(const short8*)(w1p + ((size_t)((kt * 2 + ph) * 8 + wv * 2 + 1) * 64 + lane) * 8);
#pragma unroll
            for (int ea = 0; ea < 4; ++ea) {
                acc[ea][0] = __builtin_amdgcn_mfma_f32_16x16x32_bf16(a[ea], bA, acc[ea][0], 0, 0, 0);
                acc[ea][1] = __builtin_amdgcn_mfma_f32_16x16x32_bf16(a[ea], bB, acc[ea][1], 0, 0, 0);
            }
        }
    }

    // ---- dist2 row + bias + silu -> m1 (bf16) into LDS [e][c] ----
    {
        float w256v[2], b1v[2];
#pragma unroll
        for (int ci = 0; ci < 2; ++ci) {
            int c = wv * 32 + ci * 16 + cbase;
            w256v[ci] = w1r256[c];
            b1v[ci]   = b1[c];
        }
#pragma unroll
        for (int ea = 0; ea < 4; ++ea)
#pragma unroll
            for (int ci = 0; ci < 2; ++ci)
#pragma unroll
                for (int rr = 0; rr < 4; ++rr) {
                    int e = ea * 16 + kgrp * 4 + rr;
                    float v = silu_f(acc[ea][ci][rr] + dist2_lds[e] * w256v[ci] + b1v[ci]);
                    m1lds[e * M1STR + wv * 32 + ci * 16 + cbase] = (short)f2bf(v);
                }
    }
    __syncthreads();                                     // B2: m1 ready

    // ---- MLP2: K=128, A from LDS m1, B direct from L2, no barriers ----
    f32x4 acc2[4][2];
#pragma unroll
    for (int ea = 0; ea < 4; ++ea)
#pragma unroll
        for (int ci = 0; ci < 2; ++ci) acc2[ea][ci] = (f32x4){0.f, 0.f, 0.f, 0.f};

#pragma unroll
    for (int kt = 0; kt < 4; ++kt) {
        short8 a[4];
#pragma unroll
        for (int ea = 0; ea < 4; ++ea)
            a[ea] = *(const short8*)&m1lds[(ea * 16 + cbase) * M1STR + kt * 32 + kgrp * 8];
#pragma unroll
        for (int ph = 0; ph < 2; ++ph) {
            short8 bA = *(const short8*)(w2p + ((size_t)((kt * 2 + ph) * 8 + wv * 2 + 0) * 64 + lane) * 8);
            short8 bB = *(const short8*)(w2p + ((size_t)((kt * 2 + ph) * 8 + wv * 2 + 1) * 64 + lane) * 8);
#pragma unroll
            for (int ea = 0; ea < 4; ++ea) {
                acc2[ea][0] = __builtin_amdgcn_mfma_f32_16x16x32_bf16(a[ea], bA, acc2[ea][0], 0, 0, 0);
                acc2[ea][1] = __builtin_amdgcn_mfma_f32_16x16x32_bf16(a[ea], bB, acc2[ea][1], 0, 0, 0);
            }
        }
    }

    // ---- epilogue: m = silu(acc2+b2) kept in REGISTERS; coord partials ----
    {
        float b2v[2], cwv2[2];
#pragma unroll
        for (int ci = 0; ci < 2; ++ci) {
            int c = wv * 32 + ci * 16 + cbase;
            b2v[ci]  = b2[c];
            cwv2[ci] = cw[c];
        }
#pragma unroll
        for (int ea = 0; ea < 4; ++ea)
#pragma unroll
            for (int rr = 0; rr < 4; ++rr) {
                int e = ea * 16 + kgrp * 4 + rr;
                float p = 0.f;
#pragma unroll
                for (int ci = 0; ci < 2; ++ci) {
                    float v = silu_f(acc2[ea][ci][rr] + b2v[ci]);
                    acc2[ea][ci][rr] = v;
                    p += v * cwv2[ci];
                }
#pragma unroll
                for (int d = 8; d >= 1; d >>= 1) p += __shfl_xor(p, d);
                if (cbase == 0) pdot[wv][e] = p;
            }
    }
    __syncthreads();                                     // B3: pdot ready

    if (tid < ET) {
        float t = tanhf(pdot[0][tid] + pdot[1][tid] + pdot[2][tid] + pdot[3][tid] + cb[0]);
        diff_lds[0][tid] *= t;
        diff_lds[1][tid] *= t;
        diff_lds[2][tid] *= t;
    }

    // ---- register-resident segmented agg flush ----
    {
        const int S = nseg;
        for (int s = 0; s < S; ++s) {
            int lo = seg_start[s], hi = seg_start[s + 1];
            int rw = seg_row[s];
            float sm0 = 0.f, sm1 = 0.f;
#pragma unroll
            for (int ea = 0; ea < 4; ++ea)
#pragma unroll
                for (int rr = 0; rr < 4; ++rr) {
                    int e = ea * 16 + kgrp * 4 + rr;
                    bool in = (e >= lo) && (e < hi);
                    sm0 += in ? acc2[ea][0][rr] : 0.f;
                    sm1 += in ? acc2[ea][1][rr] : 0.f;
                }
            sm0 += __shfl_xor(sm0, 16); sm0 += __shfl_xor(sm0, 32);
            sm1 += __shfl_xor(sm1, 16); sm1 += __shfl_xor(sm1, 32);
            if (kgrp == 0) {
                atomicAdd(&agg[(size_t)rw * HDIM + wv * 32 + cbase], sm0);
                atomicAdd(&agg[(size_t)rw * HDIM + wv * 32 + 16 + cbase], sm1);
            }
        }
    }

    // ---- pos flush ----
    if (tid < 3) {
        int d = tid;
        float a = 0.0f;
        int prev = row_lds[0];
        for (int e = 0; e < ET; ++e) {
            int r = row_lds[e];
            if (r != prev) {
                atomicAdd(&posn[(size_t)prev * 3 + d], a);
                a = 0.0f; prev = r;
            }
            a += diff_lds[d][e];
        }
        atomicAdd(&posn[(size_t)prev * 3 + d], a);
    }
}

// ---------------------------------------------------------------------------
// h_out = silu(concat[h, agg] @ NW + nb)   (K = 256); also emit bf16 copy
// ---------------------------------------------------------------------------
__global__ __launch_bounds__(256, 2) void node_kernel(
    const float* __restrict__ h, const float* __restrict__ agg,
    const float* __restrict__ W,   // [256][128]
    const float* __restrict__ nb,  // [128]
    float* __restrict__ hout, unsigned short* __restrict__ houtbf, int N)
{
    __shared__ float Wlds[KC * HDIM];
    __shared__ float abuf[ET * 36];

    const int tid = threadIdx.x;
    const int n0 = blockIdx.x * ET;
    const int jq8 = (tid & 15) * 8;
    const int eg4 = (tid >> 4) * 4;
    const int gl_e = tid >> 2;
    const int gl_k = (tid & 3) * 8;

    float acc[4][8];
#pragma unroll
    for (int i = 0; i < 4; ++i)
#pragma unroll
        for (int j = 0; j < 8; ++j) acc[i][j] = 0.0f;

    for (int c = 0; c < 8; ++c) {
        {
            const float4* src = (const float4*)(W + (size_t)c * KC * HDIM);
            float4* dst = (float4*)Wlds;
#pragma unroll
            for (int t = 0; t < 4; ++t) dst[tid + t * 256] = src[tid + t * 256];
        }
        {
            int n = n0 + gl_e;
            int koff = (c & 3) * KC;
            float4* adst = (float4*)(abuf + gl_e * 36 + gl_k);
            if (n < N) {
                const float* base = (c < 4) ? h : agg;
                const float4* asrc = (const float4*)(base + (size_t)n * HDIM + koff + gl_k);
                adst[0] = asrc[0]; adst[1] = asrc[1];
            } else {
                float4 z = make_float4(0.f, 0.f, 0.f, 0.f);
                adst[0] = z; adst[1] = z;
            }
        }
        __syncthreads();
#pragma unroll 8
        for (int kk = 0; kk < KC; ++kk) {
            float a0 = abuf[(eg4 + 0) * 36 + kk];
            float a1 = abuf[(eg4 + 1) * 36 + kk];
            float a2 = abuf[(eg4 + 2) * 36 + kk];
            float a3 = abuf[(eg4 + 3) * 36 + kk];
            float4 w0 = *(const float4*)&Wlds[kk * HDIM + jq8];
            float4 w1 = *(const float4*)&Wlds[kk * HDIM + jq8 + 4];
            float w[8] = {w0.x, w0.y, w0.z, w0.w, w1.x, w1.y, w1.z, w1.w};
            float a[4] = {a0, a1, a2, a3};
#pragma unroll
            for (int i = 0; i < 4; ++i)
#pragma unroll
                for (int j = 0; j < 8; ++j) acc[i][j] += a[i] * w[j];
        }
        __syncthreads();
    }

    float bb[8];
    *(float4*)&bb[0] = *(const float4*)(nb + jq8);
    *(float4*)&bb[4] = *(const float4*)(nb + jq8 + 4);
#pragma unroll
    for (int i = 0; i < 4; ++i) {
        int n = n0 + eg4 + i;
        if (n < N) {
            float v[8];
#pragma unroll
            for (int j = 0; j < 8; ++j) v[j] = silu_f(acc[i][j] + bb[j]);
            *(float4*)(hout + (size_t)n * HDIM + jq8)     = make_float4(v[0], v[1], v[2], v[3]);
            *(float4*)(hout + (size_t)n * HDIM + jq8 + 4) = make_float4(v[4], v[5], v[6], v[7]);
            unsigned short* hb = houtbf + (size_t)n * HDIM + jq8;
#pragma unroll
            for (int j = 0; j < 8; ++j) hb[j] = f2bf(v[j]);
        }
    }
}

// ---------------------------------------------------------------------------
__global__ __launch_bounds__(256) void pool_kernel(
    const float* __restrict__ h, const int* __restrict__ batch,
    float* __restrict__ pooled, float* __restrict__ cnt, int N)
{
    int idx = blockIdx.x * 256 + threadIdx.x;
    int n = idx >> 5;
    int jg = idx & 31;
    if (n >= N) return;
    int b = batch[n];
    float4 v = *(const float4*)(h + (size_t)n * HDIM + jg * 4);
    atomicAdd(&pooled[(size_t)b * HDIM + jg * 4 + 0], v.x);
    atomicAdd(&pooled[(size_t)b * HDIM + jg * 4 + 1], v.y);
    atomicAdd(&pooled[(size_t)b * HDIM + jg * 4 + 2], v.z);
    atomicAdd(&pooled[(size_t)b * HDIM + jg * 4 + 3], v.w);
    if (jg == 0) atomicAdd(&cnt[b], 1.0f);
}

// ---------------------------------------------------------------------------
__global__ __launch_bounds__(128) void head_kernel(
    const float* __restrict__ pooled, const float* __restrict__ cnt,
    const float* __restrict__ W1, const float* __restrict__ b1,
    const float* __restrict__ w2, const float* __restrict__ b2,
    float* __restrict__ out)
{
    __shared__ float p[HDIM];
    __shared__ float red[2];
    int g = blockIdx.x, j = threadIdx.x;
    float c = fmaxf(cnt[g], 1.0f);
    p[j] = pooled[(size_t)g * HDIM + j] / c;
    __syncthreads();
    float s = b1[j];
#pragma unroll 8
    for (int k = 0; k < HDIM; ++k) s += p[k] * W1[k * HDIM + j];
    float contrib = silu_f(s) * w2[j];
#pragma unroll
    for (int d = 32; d >= 1; d >>= 1) contrib += __shfl_xor(contrib, d);
    if ((j & 63) == 0) red[j >> 6] = contrib;
    __syncthreads();
    if (j == 0) out[g] = red[0] + red[1] + b2[0];
}

// ---------------------------------------------------------------------------
extern "C" void kernel_launch(void* const* d_in, const int* in_sizes, int n_in,
                              void* d_out, int out_size, void* d_ws, size_t ws_size,
                              hipStream_t stream)
{
    const float* x      = (const float*)d_in[0];
    const float* pos_in = (const float*)d_in[1];
    const int*   ei     = (const int*)d_in[2];
    const int*   batch  = (const int*)d_in[3];
    const float* emb_W  = (const float*)d_in[4];
    const float* emb_b  = (const float*)d_in[5];
    const float* ew1    = (const float*)d_in[6];
    const float* eb1    = (const float*)d_in[7];
    const float* ew2    = (const float*)d_in[8];
    const float* eb2    = (const float*)d_in[9];
    const float* nw     = (const float*)d_in[10];
    const float* nb     = (const float*)d_in[11];
    const float* cwv    = (const float*)d_in[12];
    const float* cbv    = (const float*)d_in[13];
    const float* hw1    = (const float*)d_in[14];
    const float* hb1    = (const float*)d_in[15];
    const float* hw2    = (const float*)d_in[16];
    const float* hb2    = (const float*)d_in[17];
    float* out = (float*)d_out;

    const int N = in_sizes[0] / 11;
    const int E = in_sizes[2] / 2;
    const int G = out_size;
    const int* row = ei;
    const int* col = ei + E;

    float* ws = (float*)d_ws;
    float* hA     = ws;
    float* hB     = hA  + (size_t)N * HDIM;
    float* agg    = hB  + (size_t)N * HDIM;
    float* hbf_f  = agg + (size_t)N * HDIM;        // N*128 bf16 = N*64 floats
    unsigned short* hbf = (unsigned short*)hbf_f;
    float* w1p_f  = hbf_f + (size_t)N * 64;        // 4*65536 bf16 = 131072 floats
    unsigned short* w1p = (unsigned short*)w1p_f;
    float* w2p_f  = w1p_f + 131072;                // 4*32768 bf16 = 65536 floats
    unsigned short* w2p = (unsigned short*)w2p_f;
    float* posA   = w2p_f + 65536;
    float* posB   = posA + (size_t)N * 3;
    float* pooled = posB + (size_t)N * 3;
    float* cnt    = pooled + (size_t)G * HDIM;
    int*   srow   = (int*)(cnt + G);
    int*   scol   = srow + E;
    int*   cntN   = scol + E;
    int*   curN   = cntN + N;

    // ---- counting sort of edges by row (layer-invariant) ----
    hipMemsetAsync(cntN, 0, (size_t)N * sizeof(int), stream);
    count_kernel<<<(E + 255) / 256, 256, 0, stream>>>(row, cntN, E);
    scan_kernel<<<1, 1024, 0, stream>>>(cntN, curN, N);
    scatter_kernel<<<(E + 255) / 256, 256, 0, stream>>>(row, col, curN, srow, scol, E);

    // ---- prepack edge weights to split-bf16 fragment order ----
    pack_w1_kernel<<<64, 256, 0, stream>>>(ew1, w1p);
    pack_w2_kernel<<<32, 256, 0, stream>>>(ew2, w2p);

    embed_kernel<<<(N + 1) / 2, 256, 0, stream>>>(x, emb_W, emb_b, hA, hbf, N);

    const float* hcur = hA;
    float* hnext = hB;
    const float* pcur = pos_in;
    float* pbufs[2] = {posA, posB};

    for (int l = 0; l < 4; ++l) {
        float* pn = pbufs[l & 1];
        hipMemsetAsync(agg, 0, (size_t)N * HDIM * sizeof(float), stream);
        hipMemcpyAsync(pn, pcur, (size_t)N * 3 * sizeof(float),
                       hipMemcpyDeviceToDevice, stream);
        edge_kernel<<<E / ET, 256, 0, stream>>>(
            hbf, pcur, srow, scol,
            w1p + (size_t)l * 65536,
            ew1 + (size_t)l * 257 * HDIM + 256 * HDIM,
            eb1 + (size_t)l * HDIM,
            w2p + (size_t)l * 32768,
            eb2 + (size_t)l * HDIM,
            cwv + (size_t)l * HDIM, cbv + l,
            agg, pn);
        node_kernel<<<(N + ET - 1) / ET, 256, 0, stream>>>(
            hcur, agg, nw + (size_t)l * 256 * HDIM, nb + (size_t)l * HDIM,
            hnext, hbf, N);
        const float* th = hcur; hcur = hnext; hnext = (float*)th;
        pcur = pn;
    }

    hipMemsetAsync(pooled, 0, (size_t)G * (HDIM + 1) * sizeof(float), stream);
    pool_kernel<<<(N * 32 + 255) / 256, 256, 0, stream>>>(hcur, batch, pooled, cnt, N);
    head_kernel<<<G, 128, 0, stream>>>(pooled, cnt, hw1, hb1, hw2, hb2, out);
}

// Round 13
// 5645.064 us; speedup vs baseline: 1.1197x; 1.0419x over previous
//
#include <hip/hip_runtime.h>
#include <math.h>

#define HDIM 128
#define ET 64          // edges (or nodes) per block
#define M1STR 136      // m1 LDS row stride in bf16 (272 B, 16B-aligned)

typedef __attribute__((ext_vector_type(8))) short short8;
typedef __attribute__((ext_vector_type(4))) float f32x4;

__device__ __forceinline__ float silu_f(float x) {
    return x / (1.0f + __expf(-x));
}
__device__ __forceinline__ unsigned short f2bf(float f) {
    unsigned int u = __float_as_uint(f);
    u = (u + 0x7FFF + ((u >> 16) & 1)) >> 16;   // RNE
    return (unsigned short)u;
}
__device__ __forceinline__ float bf2f(unsigned short v) {
    return __uint_as_float(((unsigned int)v) << 16);
}

// ---------------------------------------------------------------------------
// h = x @ emb_W + emb_b    (N x 11 @ 11 x 128); also emit bf16 copy
// ---------------------------------------------------------------------------
__global__ __launch_bounds__(256) void embed_kernel(
    const float* __restrict__ x, const float* __restrict__ W,
    const float* __restrict__ b, float* __restrict__ h,
    unsigned short* __restrict__ hbf, int N)
{
    int n = blockIdx.x * 2 + (threadIdx.x >> 7);
    int j = threadIdx.x & 127;
    if (n >= N) return;
    float s = b[j];
#pragma unroll
    for (int k = 0; k < 11; ++k) s += x[n * 11 + k] * W[k * HDIM + j];
    h[(size_t)n * HDIM + j] = s;
    hbf[(size_t)n * HDIM + j] = f2bf(s);
}

// ---------------------------------------------------------------------------
// Counting sort of edges by row (destination). Done once per launch.
// ---------------------------------------------------------------------------
__global__ __launch_bounds__(256) void count_kernel(
    const int* __restrict__ row, int* __restrict__ cnt, int E)
{
    int e = blockIdx.x * 256 + threadIdx.x;
    if (e < E) atomicAdd(&cnt[row[e]], 1);
}

__global__ __launch_bounds__(1024) void scan_kernel(
    const int* __restrict__ cnt, int* __restrict__ cursor, int Nn)
{
    __shared__ int lds[1024];
    int t = threadIdx.x;
    int chunk = (Nn + 1023) >> 10;
    int base = t * chunk;
    int s = 0;
    for (int k = 0; k < chunk; ++k) {
        int n = base + k;
        if (n < Nn) s += cnt[n];
    }
    lds[t] = s;
    __syncthreads();
    for (int d = 1; d < 1024; d <<= 1) {
        int v = (t >= d) ? lds[t - d] : 0;
        __syncthreads();
        lds[t] += v;
        __syncthreads();
    }
    int run = lds[t] - s;
    for (int k = 0; k < chunk; ++k) {
        int n = base + k;
        if (n < Nn) { cursor[n] = run; run += cnt[n]; }
    }
}

__global__ __launch_bounds__(256) void scatter_kernel(
    const int* __restrict__ row, const int* __restrict__ col,
    int* __restrict__ cursor, int* __restrict__ srow, int* __restrict__ scol, int E)
{
    int e = blockIdx.x * 256 + threadIdx.x;
    if (e < E) {
        int r = row[e];
        int p = atomicAdd(&cursor[r], 1);
        srow[p] = r;
        scol[p] = col[e];
    }
}

// ---------------------------------------------------------------------------
// Prepack weights into bf16 MFMA B-fragment order, SPLIT hi/lo:
//   lo = bf16(W - float(hi)).  Layout per layer: [kt][ph][ct][lane][j]
// ---------------------------------------------------------------------------
__global__ __launch_bounds__(256) void pack_w1_kernel(
    const float* __restrict__ ew1, unsigned short* __restrict__ w1p)
{
    int idx = blockIdx.x * 256 + threadIdx.x;       // 16384 total
    int l    = idx >> 12;
    int kt   = (idx >> 9) & 7;
    int ct   = (idx >> 6) & 7;
    int lane = idx & 63;
    const float* src = ew1 + (size_t)l * 257 * HDIM;
    short8 hi, lo;
#pragma unroll
    for (int j = 0; j < 8; ++j) {
        float w = src[(size_t)(kt * 32 + (lane >> 4) * 8 + j) * HDIM + ct * 16 + (lane & 15)];
        unsigned short h = f2bf(w);
        hi[j] = (short)h;
        lo[j] = (short)f2bf(w - bf2f(h));
    }
    size_t base = (size_t)l * 65536;
    *(short8*)(w1p + base + ((size_t)((kt * 2 + 0) * 8 + ct) * 64 + lane) * 8) = hi;
    *(short8*)(w1p + base + ((size_t)((kt * 2 + 1) * 8 + ct) * 64 + lane) * 8) = lo;
}

__global__ __launch_bounds__(256) void pack_w2_kernel(
    const float* __restrict__ ew2, unsigned short* __restrict__ w2p)
{
    int idx = blockIdx.x * 256 + threadIdx.x;       // 8192 total
    int l    = idx >> 11;
    int kt   = (idx >> 9) & 3;
    int ct   = (idx >> 6) & 7;
    int lane = idx & 63;
    const float* src = ew2 + (size_t)l * HDIM * HDIM;
    short8 hi, lo;
#pragma unroll
    for (int j = 0; j < 8; ++j) {
        float w = src[(size_t)(kt * 32 + (lane >> 4) * 8 + j) * HDIM + ct * 16 + (lane & 15)];
        unsigned short h = f2bf(w);
        hi[j] = (short)h;
        lo[j] = (short)f2bf(w - bf2f(h));
    }
    size_t base = (size_t)l * 32768;
    *(short8*)(w2p + base + ((size_t)((kt * 2 + 0) * 8 + ct) * 64 + lane) * 8) = hi;
    *(short8*)(w2p + base + ((size_t)((kt * 2 + 1) * 8 + ct) * 64 + lane) * 8) = lo;
}

// nw: [L][256][128] -> nwp [L][8kt][2ph][8ct][64][8]
__global__ __launch_bounds__(256) void pack_nw_kernel(
    const float* __restrict__ nw, unsigned short* __restrict__ nwp)
{
    int idx = blockIdx.x * 256 + threadIdx.x;       // 16384 total
    int l    = idx >> 12;
    int kt   = (idx >> 9) & 7;
    int ct   = (idx >> 6) & 7;
    int lane = idx & 63;
    const float* src = nw + (size_t)l * 256 * HDIM;
    short8 hi, lo;
#pragma unroll
    for (int j = 0; j < 8; ++j) {
        float w = src[(size_t)(kt * 32 + (lane >> 4) * 8 + j) * HDIM + ct * 16 + (lane & 15)];
        unsigned short h = f2bf(w);
        hi[j] = (short)h;
        lo[j] = (short)f2bf(w - bf2f(h));
    }
    size_t base = (size_t)l * 65536;
    *(short8*)(nwp + base + ((size_t)((kt * 2 + 0) * 8 + ct) * 64 + lane) * 8) = hi;
    *(short8*)(nwp + base + ((size_t)((kt * 2 + 1) * 8 + ct) * 64 + lane) * 8) = lo;
}

// ---------------------------------------------------------------------------
// Barrier-light MFMA edge kernel, register-resident flush. 64 edges/block,
// 4 waves; wave wv owns output cols [wv*32, wv*32+32) of ALL 64 edges.
// launch_bounds(256,4): unified VGPR cap 128 -> no spill (r12's (256,5)
// cap ~102 < ~112 needed -> 490 MB scratch traffic).
// ---------------------------------------------------------------------------
__global__ __launch_bounds__(256, 4) void edge_kernel(
    const unsigned short* __restrict__ hbf,  // [N,128] bf16
    const float* __restrict__ pos,           // [N,3]
    const int*   __restrict__ row,           // sorted
    const int*   __restrict__ col,
    const unsigned short* __restrict__ w1p,  // [8][2][8][64][8] bf16 frags
    const float* __restrict__ w1r256,        // W1 row 256 (f32[128])
    const float* __restrict__ b1,            // [128]
    const unsigned short* __restrict__ w2p,  // [4][2][8][64][8]
    const float* __restrict__ b2,            // [128]
    const float* __restrict__ cw,            // [128]
    const float* __restrict__ cb,            // [1]
    float* __restrict__ agg,                 // [N,128]
    float* __restrict__ posn)                // [N,3]
{
    __shared__ __align__(16) short m1lds[ET * M1STR];    // 17.4 KB
    __shared__ float diff_lds[3][ET];
    __shared__ float dist2_lds[ET];
    __shared__ float pdot[4][ET];
    __shared__ int   row_lds[ET];
    __shared__ int   col_lds[ET];
    __shared__ int   seg_start[ET + 2];
    __shared__ int   seg_row[ET];
    __shared__ int   nseg;

    const int tid  = threadIdx.x;
    const int lane = tid & 63;
    const int wv   = tid >> 6;
    const int cbase = lane & 15;
    const int kgrp  = lane >> 4;
    const long long e0 = (long long)blockIdx.x * ET;

    if (tid < ET) {
        long long e = e0 + tid;
        int r = row[e], c = col[e];
        int rprev = (tid > 0) ? row[e - 1] : -1;
        row_lds[tid] = r; col_lds[tid] = c;
        float dx = pos[r * 3 + 0] - pos[c * 3 + 0];
        float dy = pos[r * 3 + 1] - pos[c * 3 + 1];
        float dz = pos[r * 3 + 2] - pos[c * 3 + 2];
        diff_lds[0][tid] = dx; diff_lds[1][tid] = dy; diff_lds[2][tid] = dz;
        dist2_lds[tid] = dx * dx + dy * dy + dz * dz;
        bool flag = (tid == 0) || (r != rprev);
        unsigned long long mask = __ballot(flag);
        int sid = __popcll(mask & (((unsigned long long)1 << tid) - 1));
        if (flag) { seg_start[sid] = tid; seg_row[sid] = r; }
        if (tid == 63) { int S = __popcll(mask); nseg = S; seg_start[S] = ET; }
    }
    __syncthreads();                                     // B1

    int ridx[4], cidx[4];
#pragma unroll
    for (int ea = 0; ea < 4; ++ea) {
        ridx[ea] = row_lds[ea * 16 + cbase];
        cidx[ea] = col_lds[ea * 16 + cbase];
    }

    // ---- MLP1: K=256, B-frags direct from L2, no barriers ----
    f32x4 acc[4][2];
#pragma unroll
    for (int ea = 0; ea < 4; ++ea)
#pragma unroll
        for (int ci = 0; ci < 2; ++ci) acc[ea][ci] = (f32x4){0.f, 0.f, 0.f, 0.f};

#pragma unroll
    for (int kt = 0; kt < 8; ++kt) {
        short8 a[4];
#pragma unroll
        for (int ea = 0; ea < 4; ++ea) {
            int idx = (kt < 4) ? ridx[ea] : cidx[ea];
            a[ea] = *(const short8*)(hbf + (size_t)idx * HDIM + (kt & 3) * 32 + kgrp * 8);
        }
#pragma unroll
        for (int ph = 0; ph < 2; ++ph) {
            short8 bA = *(const short8*)(w1p + ((size_t)((kt * 2 + ph) * 8 + wv * 2 + 0) * 64 + lane) * 8);
            short8 bB = *(const short8*)(w1p + ((size_t)((kt * 2 + ph) * 8 + wv * 2 + 1) * 64 + lane) * 8);
#pragma unroll
            for (int ea = 0; ea < 4; ++ea) {
                acc[ea][0] = __builtin_amdgcn_mfma_f32_16x16x32_bf16(a[ea], bA, acc[ea][0], 0, 0, 0);
                acc[ea][1] = __builtin_amdgcn_mfma_f32_16x16x32_bf16(a[ea], bB, acc[ea][1], 0, 0, 0);
            }
        }
    }

    // ---- dist2 row + bias + silu -> m1 (bf16) into LDS [e][c] ----
    {
        float w256v[2], b1v[2];
#pragma unroll
        for (int ci = 0; ci < 2; ++ci) {
            int c = wv * 32 + ci * 16 + cbase;
            w256v[ci] = w1r256[c];
            b1v[ci]   = b1[c];
        }
#pragma unroll
        for (int ea = 0; ea < 4; ++ea)
#pragma unroll
            for (int ci = 0; ci < 2; ++ci)
#pragma unroll
                for (int rr = 0; rr < 4; ++rr) {
                    int e = ea * 16 + kgrp * 4 + rr;
                    float v = silu_f(acc[ea][ci][rr] + dist2_lds[e] * w256v[ci] + b1v[ci]);
                    m1lds[e * M1STR + wv * 32 + ci * 16 + cbase] = (short)f2bf(v);
                }
    }
    __syncthreads();                                     // B2: m1 ready

    // ---- MLP2: K=128, A from LDS m1, B direct from L2, no barriers ----
    f32x4 acc2[4][2];
#pragma unroll
    for (int ea = 0; ea < 4; ++ea)
#pragma unroll
        for (int ci = 0; ci < 2; ++ci) acc2[ea][ci] = (f32x4){0.f, 0.f, 0.f, 0.f};

#pragma unroll
    for (int kt = 0; kt < 4; ++kt) {
        short8 a[4];
#pragma unroll
        for (int ea = 0; ea < 4; ++ea)
            a[ea] = *(const short8*)&m1lds[(ea * 16 + cbase) * M1STR + kt * 32 + kgrp * 8];
#pragma unroll
        for (int ph = 0; ph < 2; ++ph) {
            short8 bA = *(const short8*)(w2p + ((size_t)((kt * 2 + ph) * 8 + wv * 2 + 0) * 64 + lane) * 8);
            short8 bB = *(const short8*)(w2p + ((size_t)((kt * 2 + ph) * 8 + wv * 2 + 1) * 64 + lane) * 8);
#pragma unroll
            for (int ea = 0; ea < 4; ++ea) {
                acc2[ea][0] = __builtin_amdgcn_mfma_f32_16x16x32_bf16(a[ea], bA, acc2[ea][0], 0, 0, 0);
                acc2[ea][1] = __builtin_amdgcn_mfma_f32_16x16x32_bf16(a[ea], bB, acc2[ea][1], 0, 0, 0);
            }
        }
    }

    // ---- epilogue: m = silu(acc2+b2) kept in REGISTERS; coord partials ----
    {
        float b2v[2], cwv2[2];
#pragma unroll
        for (int ci = 0; ci < 2; ++ci) {
            int c = wv * 32 + ci * 16 + cbase;
            b2v[ci]  = b2[c];
            cwv2[ci] = cw[c];
        }
#pragma unroll
        for (int ea = 0; ea < 4; ++ea)
#pragma unroll
            for (int rr = 0; rr < 4; ++rr) {
                int e = ea * 16 + kgrp * 4 + rr;
                float p = 0.f;
#pragma unroll
                for (int ci = 0; ci < 2; ++ci) {
                    float v = silu_f(acc2[ea][ci][rr] + b2v[ci]);
                    acc2[ea][ci][rr] = v;
                    p += v * cwv2[ci];
                }
#pragma unroll
                for (int d = 8; d >= 1; d >>= 1) p += __shfl_xor(p, d);
                if (cbase == 0) pdot[wv][e] = p;
            }
    }
    __syncthreads();                                     // B3: pdot ready

    if (tid < ET) {
        float t = tanhf(pdot[0][tid] + pdot[1][tid] + pdot[2][tid] + pdot[3][tid] + cb[0]);
        diff_lds[0][tid] *= t;
        diff_lds[1][tid] *= t;
        diff_lds[2][tid] *= t;
    }

    // ---- register-resident segmented agg flush ----
    {
        const int S = nseg;
        for (int s = 0; s < S; ++s) {
            int lo = seg_start[s], hi = seg_start[s + 1];
            int rw = seg_row[s];
            float sm0 = 0.f, sm1 = 0.f;
#pragma unroll
            for (int ea = 0; ea < 4; ++ea)
#pragma unroll
                for (int rr = 0; rr < 4; ++rr) {
                    int e = ea * 16 + kgrp * 4 + rr;
                    bool in = (e >= lo) && (e < hi);
                    sm0 += in ? acc2[ea][0][rr] : 0.f;
                    sm1 += in ? acc2[ea][1][rr] : 0.f;
                }
            sm0 += __shfl_xor(sm0, 16); sm0 += __shfl_xor(sm0, 32);
            sm1 += __shfl_xor(sm1, 16); sm1 += __shfl_xor(sm1, 32);
            if (kgrp == 0) {
                atomicAdd(&agg[(size_t)rw * HDIM + wv * 32 + cbase], sm0);
                atomicAdd(&agg[(size_t)rw * HDIM + wv * 32 + 16 + cbase], sm1);
            }
        }
    }

    // ---- pos flush ----
    if (tid < 3) {
        int d = tid;
        float a = 0.0f;
        int prev = row_lds[0];
        for (int e = 0; e < ET; ++e) {
            int r = row_lds[e];
            if (r != prev) {
                atomicAdd(&posn[(size_t)prev * 3 + d], a);
                a = 0.0f; prev = r;
            }
            a += diff_lds[d][e];
        }
        atomicAdd(&posn[(size_t)prev * 3 + d], a);
    }
}

// ---------------------------------------------------------------------------
// MFMA node kernel: h_out = silu(concat[hbf, agg] @ NW + nb).
// 64 nodes/block, 4 waves x 32 cols, zero LDS, zero barriers.
// A: kt<4 from hbf; kt>=4 from agg (fp32 -> bf16 in-register).
// ---------------------------------------------------------------------------
__global__ __launch_bounds__(256, 4) void node_kernel(
    const unsigned short* __restrict__ hbf,  // [N,128] bf16
    const float* __restrict__ agg,           // [N,128] f32
    const unsigned short* __restrict__ nwp,  // [8][2][8][64][8] bf16 frags
    const float* __restrict__ nb,            // [128]
    float* __restrict__ hout, unsigned short* __restrict__ houtbf, int N)
{
    const int tid  = threadIdx.x;
    const int lane = tid & 63;
    const int wv   = tid >> 6;
    const int cbase = lane & 15;
    const int kgrp  = lane >> 4;
    const int n0 = blockIdx.x * ET;

    f32x4 acc[4][2];
#pragma unroll
    for (int ea = 0; ea < 4; ++ea)
#pragma unroll
        for (int ci = 0; ci < 2; ++ci) acc[ea][ci] = (f32x4){0.f, 0.f, 0.f, 0.f};

#pragma unroll
    for (int kt = 0; kt < 8; ++kt) {
        short8 a[4];
#pragma unroll
        for (int ea = 0; ea < 4; ++ea) {
            int n = n0 + ea * 16 + cbase;
            int ns = (n < N) ? n : 0;
            if (kt < 4) {
                a[ea] = *(const short8*)(hbf + (size_t)ns * HDIM + kt * 32 + kgrp * 8);
            } else {
                const float* src = agg + (size_t)ns * HDIM + (kt - 4) * 32 + kgrp * 8;
                float4 v0 = *(const float4*)src;
                float4 v1 = *(const float4*)(src + 4);
                short8 t;
                t[0] = (short)f2bf(v0.x); t[1] = (short)f2bf(v0.y);
                t[2] = (short)f2bf(v0.z); t[3] = (short)f2bf(v0.w);
                t[4] = (short)f2bf(v1.x); t[5] = (short)f2bf(v1.y);
                t[6] = (short)f2bf(v1.z); t[7] = (short)f2bf(v1.w);
                a[ea] = t;
            }
        }
#pragma unroll
        for (int ph = 0; ph < 2; ++ph) {
            short8 bA = *(const short8*)(nwp + ((size_t)((kt * 2 + ph) * 8 + wv * 2 + 0) * 64 + lane) * 8);
            short8 bB = *(const short8*)(nwp + ((size_t)((kt * 2 + ph) * 8 + wv * 2 + 1) * 64 + lane) * 8);
#pragma unroll
            for (int ea = 0; ea < 4; ++ea) {
                acc[ea][0] = __builtin_amdgcn_mfma_f32_16x16x32_bf16(a[ea], bA, acc[ea][0], 0, 0, 0);
                acc[ea][1] = __builtin_amdgcn_mfma_f32_16x16x32_bf16(a[ea], bB, acc[ea][1], 0, 0, 0);
            }
        }
    }

    // epilogue: silu + store fp32 + bf16
    {
        float nbv[2];
#pragma unroll
        for (int ci = 0; ci < 2; ++ci) nbv[ci] = nb[wv * 32 + ci * 16 + cbase];
#pragma unroll
        for (int ea = 0; ea < 4; ++ea)
#pragma unroll
            for (int rr = 0; rr < 4; ++rr) {
                int n = n0 + ea * 16 + kgrp * 4 + rr;
                if (n < N) {
#pragma unroll
                    for (int ci = 0; ci < 2; ++ci) {
                        int c = wv * 32 + ci * 16 + cbase;
                        float v = silu_f(acc[ea][ci][rr] + nbv[ci]);
                        hout[(size_t)n * HDIM + c] = v;
                        houtbf[(size_t)n * HDIM + c] = f2bf(v);
                    }
                }
            }
    }
}

// ---------------------------------------------------------------------------
__global__ __launch_bounds__(256) void pool_kernel(
    const float* __restrict__ h, const int* __restrict__ batch,
    float* __restrict__ pooled, float* __restrict__ cnt, int N)
{
    int idx = blockIdx.x * 256 + threadIdx.x;
    int n = idx >> 5;
    int jg = idx & 31;
    if (n >= N) return;
    int b = batch[n];
    float4 v = *(const float4*)(h + (size_t)n * HDIM + jg * 4);
    atomicAdd(&pooled[(size_t)b * HDIM + jg * 4 + 0], v.x);
    atomicAdd(&pooled[(size_t)b * HDIM + jg * 4 + 1], v.y);
    atomicAdd(&pooled[(size_t)b * HDIM + jg * 4 + 2], v.z);
    atomicAdd(&pooled[(size_t)b * HDIM + jg * 4 + 3], v.w);
    if (jg == 0) atomicAdd(&cnt[b], 1.0f);
}

// ---------------------------------------------------------------------------
__global__ __launch_bounds__(128) void head_kernel(
    const float* __restrict__ pooled, const float* __restrict__ cnt,
    const float* __restrict__ W1, const float* __restrict__ b1,
    const float* __restrict__ w2, const float* __restrict__ b2,
    float* __restrict__ out)
{
    __shared__ float p[HDIM];
    __shared__ float red[2];
    int g = blockIdx.x, j = threadIdx.x;
    float c = fmaxf(cnt[g], 1.0f);
    p[j] = pooled[(size_t)g * HDIM + j] / c;
    __syncthreads();
    float s = b1[j];
#pragma unroll 8
    for (int k = 0; k < HDIM; ++k) s += p[k] * W1[k * HDIM + j];
    float contrib = silu_f(s) * w2[j];
#pragma unroll
    for (int d = 32; d >= 1; d >>= 1) contrib += __shfl_xor(contrib, d);
    if ((j & 63) == 0) red[j >> 6] = contrib;
    __syncthreads();
    if (j == 0) out[g] = red[0] + red[1] + b2[0];
}

// ---------------------------------------------------------------------------
extern "C" void kernel_launch(void* const* d_in, const int* in_sizes, int n_in,
                              void* d_out, int out_size, void* d_ws, size_t ws_size,
                              hipStream_t stream)
{
    const float* x      = (const float*)d_in[0];
    const float* pos_in = (const float*)d_in[1];
    const int*   ei     = (const int*)d_in[2];
    const int*   batch  = (const int*)d_in[3];
    const float* emb_W  = (const float*)d_in[4];
    const float* emb_b  = (const float*)d_in[5];
    const float* ew1    = (const float*)d_in[6];
    const float* eb1    = (const float*)d_in[7];
    const float* ew2    = (const float*)d_in[8];
    const float* eb2    = (const float*)d_in[9];
    const float* nw     = (const float*)d_in[10];
    const float* nb     = (const float*)d_in[11];
    const float* cwv    = (const float*)d_in[12];
    const float* cbv    = (const float*)d_in[13];
    const float* hw1    = (const float*)d_in[14];
    const float* hb1    = (const float*)d_in[15];
    const float* hw2    = (const float*)d_in[16];
    const float* hb2    = (const float*)d_in[17];
    float* out = (float*)d_out;

    const int N = in_sizes[0] / 11;
    const int E = in_sizes[2] / 2;
    const int G = out_size;
    const int* row = ei;
    const int* col = ei + E;

    float* ws = (float*)d_ws;
    float* hA     = ws;
    float* hB     = hA  + (size_t)N * HDIM;
    float* agg    = hB  + (size_t)N * HDIM;
    float* hbf_f  = agg + (size_t)N * HDIM;        // N*128 bf16 = N*64 floats
    unsigned short* hbf = (unsigned short*)hbf_f;
    float* w1p_f  = hbf_f + (size_t)N * 64;        // 4*65536 bf16 = 131072 floats
    unsigned short* w1p = (unsigned short*)w1p_f;
    float* w2p_f  = w1p_f + 131072;                // 4*32768 bf16 = 65536 floats
    unsigned short* w2p = (unsigned short*)w2p_f;
    float* nwp_f  = w2p_f + 65536;                 // 4*65536 bf16 = 131072 floats
    unsigned short* nwp = (unsigned short*)nwp_f;
    float* posA   = nwp_f + 131072;
    float* posB   = posA + (size_t)N * 3;
    float* pooled = posB + (size_t)N * 3;
    float* cnt    = pooled + (size_t)G * HDIM;
    int*   srow   = (int*)(cnt + G);
    int*   scol   = srow + E;
    int*   cntN   = scol + E;
    int*   curN   = cntN + N;

    // ---- counting sort of edges by row (layer-invariant) ----
    hipMemsetAsync(cntN, 0, (size_t)N * sizeof(int), stream);
    count_kernel<<<(E + 255) / 256, 256, 0, stream>>>(row, cntN, E);
    scan_kernel<<<1, 1024, 0, stream>>>(cntN, curN, N);
    scatter_kernel<<<(E + 255) / 256, 256, 0, stream>>>(row, col, curN, srow, scol, E);

    // ---- prepack weights to split-bf16 fragment order ----
    pack_w1_kernel<<<64, 256, 0, stream>>>(ew1, w1p);
    pack_w2_kernel<<<32, 256, 0, stream>>>(ew2, w2p);
    pack_nw_kernel<<<64, 256, 0, stream>>>(nw, nwp);

    embed_kernel<<<(N + 1) / 2, 256, 0, stream>>>(x, emb_W, emb_b, hA, hbf, N);

    const float* hcur = hA;
    float* hnext = hB;
    const float* pcur = pos_in;
    float* pbufs[2] = {posA, posB};

    for (int l = 0; l < 4; ++l) {
        float* pn = pbufs[l & 1];
        hipMemsetAsync(agg, 0, (size_t)N * HDIM * sizeof(float), stream);
        hipMemcpyAsync(pn, pcur, (size_t)N * 3 * sizeof(float),
                       hipMemcpyDeviceToDevice, stream);
        edge_kernel<<<E / ET, 256, 0, stream>>>(
            hbf, pcur, srow, scol,
            w1p + (size_t)l * 65536,
            ew1 + (size_t)l * 257 * HDIM + 256 * HDIM,
            eb1 + (size_t)l * HDIM,
            w2p + (size_t)l * 32768,
            eb2 + (size_t)l * HDIM,
            cwv + (size_t)l * HDIM, cbv + l,
            agg, pn);
        node_kernel<<<(N + ET - 1) / ET, 256, 0, stream>>>(
            hbf, agg, nwp + (size_t)l * 65536, nb + (size_t)l * HDIM,
            hnext, hbf, N);
        const float* th = hcur; hcur = hnext; hnext = (float*)th;
        pcur = pn;
    }

    hipMemsetAsync(pooled, 0, (size_t)G * (HDIM + 1) * sizeof(float), stream);
    pool_kernel<<<(N * 32 + 255) / 256, 256, 0, stream>>>(hcur, batch, pooled, cnt, N);
    head_kernel<<<G, 128, 0, stream>>>(pooled, cnt, hw1, hb1, hw2, hb2, out);
}